// Round 4
// baseline (429.704 us; speedup 1.0000x reference)
//
#include <hip/hip_runtime.h>
#include <math.h>

// DILATE loss: 0.5*mean(softDTW) + 0.5*sum(E*Omega)/(B*N*N) + MSE
// B=64, N=256, K=1, gamma=0.01.
//
// One wave per batch, lane p owns rows 4p+1..4p+4. Skew-2 anti-diagonal
// pipeline (lane p does column j=s-2p+1 at step s fwd, j=N-u+2(63-p) bwd);
// cross-lane values travel via 2-step-delayed shuffles. This round: loops are
// BRANCHLESS (unconditional compute, predicated state updates) and unrolled
// x4 so the compiler can rotate registers and space s_waitcnt (store-ack /
// load latency hidden across 4 iterations instead of vmcnt(0) every step).
//
// ws: [0, 64*382*64*16 B ≈ 25 MB) R slabs [b][s][p]; then 64*3 doubles.

#define BB 64
#define NN 256
#define PP 64
#define NSLAB (NN + 2 * (PP - 1))  // 382 real slabs
#define NPAD 384                   // padded loop count (%4==0); pad steps inactive
#define INF_F 100000000.0f
#define ESC 144.26950408889634f   /* (1/gamma) * log2(e) */
#define LSC 0.006931471805599453f /* gamma * ln(2) */

__device__ __forceinline__ float fwd_cell(float a, float b, float c, float ti, float xj) {
  const float m = fminf(a, fminf(b, c));
  const float s = exp2f((m - a) * ESC) + exp2f((m - b) * ESC) + exp2f((m - c) * ESC);
  const float smin = m - LSC * log2f(s);
  const float dx = ti - xj;
  return fmaf(dx, dx, smin);
}

__global__ __launch_bounds__(64) void sdtw_kernel(
    const float* __restrict__ input, const float* __restrict__ target,
    float4* __restrict__ Rws, double* __restrict__ partial) {
  const int b = blockIdx.x;
  const int p = threadIdx.x;
  __shared__ float xs[NN];

  const float4 xv4 = ((const float4*)(input + b * NN))[p];
  const float4 tv4 = ((const float4*)(target + b * NN))[p];
  ((float4*)xs)[p] = xv4;
  const float t0 = tv4.x, t1 = tv4.y, t2 = tv4.z, t3 = tv4.w;
  const float t4 = __shfl_down(t0, 1);  // t of lane p+1's top row (pb-guarded use)
  __syncthreads();

  double msel;
  {
    const float d0 = xv4.x - tv4.x, d1 = xv4.y - tv4.y;
    const float d2 = xv4.z - tv4.z, d3 = xv4.w - tv4.w;
    msel = (double)(d0 * d0) + (double)(d1 * d1) + (double)(d2 * d2) + (double)(d3 * d3);
  }

  float4* __restrict__ Rb = Rws + (size_t)b * NSLAB * PP;

  // ---------------- forward (skew 2, branchless, unroll 4) ----------------
  float prev0 = INF_F, prev1 = INF_F, prev2 = INF_F, prev3 = INF_F;
  float tl = (p == 0) ? 0.0f : INF_F;  // R[4p][j-1]
  float ttop = INF_F;                  // R[4p][j]
  float ttop_s1 = INF_F;               // delay slot (arrives for step s+1)
  float x_use = xs[0];                 // x[j-1] this step
  float x_s1 = xs[1];                  // delay slot
#pragma unroll 4
  for (int s = 0; s < NPAD; ++s) {
    const float xpre = xs[(s + 2 < NN) ? (s + 2) : (NN - 1)];  // lane0 injection for s+2
    const int j = s - 2 * p + 1;
    const bool act = (j >= 1) & (j <= NN);
    // unconditional compute; garbage (INF-propagated) outside the window is
    // discarded by the selects below and never exported (bot is predicated).
    const float c0 = fwd_cell(tl, ttop, prev0, t0, x_use);
    const float c1 = fwd_cell(prev0, c0, prev1, t1, x_use);
    const float c2 = fwd_cell(prev1, c1, prev2, t2, x_use);
    const float c3 = fwd_cell(prev2, c2, prev3, t3, x_use);
    if (act) Rb[(size_t)s * PP + p] = make_float4(c0, c1, c2, c3);
    prev0 = act ? c0 : prev0;
    prev1 = act ? c1 : prev1;
    prev2 = act ? c2 : prev2;
    prev3 = act ? c3 : prev3;
    const float bot = act ? c3 : INF_F;     // INF outside window is never consumed
    const float shN = __shfl_up(bot, 1);    // lane p-1's R[4p][j+2] (use at s+2)
    const float xsh = __shfl_up(x_use, 1);  // lane p-1's x (use at s+2)
    tl = ttop;
    ttop = ttop_s1;
    ttop_s1 = (p == 0) ? INF_F : shN;
    x_use = x_s1;
    x_s1 = (p == 0) ? xpre : xsh;
  }
  const float r_nn = __shfl(prev3, PP - 1);  // frozen R[N][N]

  __builtin_amdgcn_s_waitcnt(0);  // drain forward stores before backward loads

  // ---------------- backward (skew 2, branchless, unroll 4) ----------------
  // E[i][j] = sum over successors of exp((R_s - D_s - R_ij)/g) * E_s; E[N][N]=1.
  float Rr0 = 0.f, Rr1 = 0.f, Rr2 = 0.f, Rr3 = 0.f;  // R[rows][j+1] (own lane)
  float Er0 = 0.f, Er1 = 0.f, Er2 = 0.f, Er3 = 0.f;  // E[rows][j+1]
  float bR0 = 0.f, bR1 = 0.f, bE0 = 0.f, bE1 = 0.f;  // R/E[4p+5][j], [4p+5][j+1]
  float bR_s1 = 0.f, bE_s1 = 0.f;                    // delay slots
  float xlo = xs[NN - 1];     // x[j-1]
  float xhi = xs[NN - 1];     // x[j] (unused at j==N)
  float xlo_s1 = xs[NN - 2];  // delay slot
  float4 Rc = Rb[(size_t)(NSLAB - 1) * PP + p];     // slab for u=0
  float4 Rc_s1 = Rb[(size_t)(NSLAB - 2) * PP + p];  // slab for u=1
  double tsum = 0.0;

#pragma unroll 4
  for (int u = 0; u < NPAD; ++u) {
    const int sp = NSLAB - 3 - u;  // slab for u+2
    const float4 Rnew = Rb[(size_t)(sp < 0 ? 0 : sp) * PP + p];
    const float xpre = xs[(NN - 3 - u) >= 0 ? (NN - 3 - u) : 0];  // lane63 injection
    const int j = NN - u + 2 * (PP - 1 - p);
    const bool act = (j >= 1) & (j <= NN);
    const bool jr = act & (j < NN);
    const bool pb = (p < PP - 1);
    // k=3 (row 4p+4): successors (i+1,j) via bR0/bE0, (i,j+1) own, (i+1,j+1) via bR1/bE1
    float da3 = t4 - xlo;
    float w3 = pb ? exp2f((bR0 - da3 * da3 - Rc.w) * ESC) * bE0 : 0.0f;
    float dr3 = t3 - xhi;
    w3 += jr ? exp2f((Rr3 - dr3 * dr3 - Rc.w) * ESC) * Er3 : 0.0f;
    float dd3 = t4 - xhi;
    w3 += (pb & jr) ? exp2f((bR1 - dd3 * dd3 - Rc.w) * ESC) * bE1 : 0.0f;
    const float e3 = ((p == PP - 1) & (u == 0)) ? 1.0f : w3;  // seed E[N][N]
    // k=2
    float da2 = t3 - xlo;
    float w2 = exp2f((Rc.w - da2 * da2 - Rc.z) * ESC) * e3;
    float dr2 = t2 - xhi;
    w2 += jr ? exp2f((Rr2 - dr2 * dr2 - Rc.z) * ESC) * Er2 : 0.0f;
    float dd2 = t3 - xhi;
    w2 += jr ? exp2f((Rr3 - dd2 * dd2 - Rc.z) * ESC) * Er3 : 0.0f;
    const float e2 = w2;
    // k=1
    float da1 = t2 - xlo;
    float w1 = exp2f((Rc.z - da1 * da1 - Rc.y) * ESC) * e2;
    float dr1 = t1 - xhi;
    w1 += jr ? exp2f((Rr1 - dr1 * dr1 - Rc.y) * ESC) * Er1 : 0.0f;
    float dd1 = t2 - xhi;
    w1 += jr ? exp2f((Rr2 - dd1 * dd1 - Rc.y) * ESC) * Er2 : 0.0f;
    const float e1 = w1;
    // k=0 (row 4p+1)
    float da0 = t1 - xlo;
    float w0 = exp2f((Rc.y - da0 * da0 - Rc.x) * ESC) * e1;
    float dr0 = t0 - xhi;
    w0 += jr ? exp2f((Rr0 - dr0 * dr0 - Rc.x) * ESC) * Er0 : 0.0f;
    float dd0 = t1 - xhi;
    w0 += jr ? exp2f((Rr1 - dd0 * dd0 - Rc.x) * ESC) * Er1 : 0.0f;
    const float e0 = w0;
    // temporal accumulation: i_k = 4p+k+1, Omega = (i-j)^2
    const float f0 = (float)(4 * p + 1 - j);
    const float f1 = f0 + 1.0f, f2 = f0 + 2.0f, f3 = f0 + 3.0f;
    const double cd = (double)(e0 * f0 * f0) + (double)(e1 * f1 * f1) +
                      (double)(e2 * f2 * f2) + (double)(e3 * f3 * f3);
    tsum += act ? cd : 0.0;
    // predicated state updates (freeze outside window; kill NaN propagation)
    Rr0 = act ? Rc.x : Rr0;
    Rr1 = act ? Rc.y : Rr1;
    Rr2 = act ? Rc.z : Rr2;
    Rr3 = act ? Rc.w : Rr3;
    Er0 = act ? e0 : Er0;
    Er1 = act ? e1 : Er1;
    Er2 = act ? e2 : Er2;
    Er3 = act ? e3 : Er3;
    // 2-step-delay pipelines (all lanes execute)
    const float sR = __shfl_down(act ? Rc.x : 0.0f, 1);
    const float sE = __shfl_down(act ? e0 : 0.0f, 1);
    const float sxl = __shfl_down(xlo, 1);
    bR1 = bR0; bE1 = bE0;
    bR0 = bR_s1; bE0 = bE_s1;
    bR_s1 = sR; bE_s1 = sE;
    xhi = xlo;
    xlo = xlo_s1;
    xlo_s1 = (p == PP - 1) ? xpre : sxl;
    Rc = Rc_s1;
    Rc_s1 = Rnew;
  }

  // ---------------- wave reductions ----------------
  for (int off = 32; off > 0; off >>= 1) {
    tsum += __shfl_xor(tsum, off);
    msel += __shfl_xor(msel, off);
  }
  if (p == 0) {
    partial[b * 3 + 0] = (double)r_nn;
    partial[b * 3 + 1] = tsum;
    partial[b * 3 + 2] = msel;
  }
}

__global__ __launch_bounds__(64) void finalize_kernel(const double* __restrict__ partial,
                                                      float* __restrict__ out) {
  const int t = threadIdx.x;  // one lane per batch
  double sd = partial[t * 3 + 0];
  double ts = partial[t * 3 + 1];
  double ms = partial[t * 3 + 2];
  for (int off = 32; off > 0; off >>= 1) {
    sd += __shfl_xor(sd, off);
    ts += __shfl_xor(ts, off);
    ms += __shfl_xor(ms, off);
  }
  if (t == 0) {
    const double loss_shape = sd / (double)BB;
    const double loss_temporal = ts / ((double)BB * NN * NN);
    const double mse = ms / ((double)BB * NN);
    out[0] = (float)(0.5 * loss_shape + 0.5 * loss_temporal + mse);
  }
}

extern "C" void kernel_launch(void* const* d_in, const int* in_sizes, int n_in,
                              void* d_out, int out_size, void* d_ws, size_t ws_size,
                              hipStream_t stream) {
  const float* input = (const float*)d_in[0];
  const float* target = (const float*)d_in[1];
  float4* Rws = (float4*)d_ws;
  double* partial = (double*)((char*)d_ws + (size_t)BB * NSLAB * PP * sizeof(float4));
  float* out = (float*)d_out;

  sdtw_kernel<<<BB, PP, 0, stream>>>(input, target, Rws, partial);
  finalize_kernel<<<1, 64, 0, stream>>>(partial, out);
}

// Round 5
// 391.242 us; speedup vs baseline: 1.0983x; 1.0983x over previous
//
#include <hip/hip_runtime.h>
#include <math.h>

// DILATE loss: 0.5*mean(softDTW) + 0.5*sum(E*Omega)/(B*N*N) + MSE
// B=64, N=256, K=1, gamma=0.01.
//
// One wave per batch, lane p owns rows 4p+1..4p+4, skew-1 anti-diagonal
// pipeline (lane p does column j = s-p+1 at step s forward, j = 319-u-p
// backward). Cross-lane R boundary travels via 1-step __shfl relay; x values
// are read directly from LDS with 2-step prefetch (no shuffle relay).
//
// KEY CHANGES vs prior rounds (attack the dependent-latency chain):
//  * Forward propagates (C,S) with R = C - gamma*ln(S): softmin needs NO log2
//    on the loop-carried chain (exp((M-R)/g) = S*exp2((M-C)*ESC); M=min(C) is
//    a valid shift since gamma*ln(S) <= 0.027, S in [1,6.5]). log2 only to
//    materialize stored R, off-chain.
//  * Backward: all 12 transition weights depend only on R (slabs prefetched
//    3 deep) and 1-step-old shuffles -- never on current E. E-chain = 4 fma.
//  * fwd/bwd split into two kernels for per-phase counter attribution.
//
// ws: [0, 64*319*64*16 B = 20.9 MB) R slabs [b][s][p]; then 64*4 doubles.

#define BB 64
#define NN 256
#define PP 64
#define NSLAB (NN + PP - 1)  // 319
#define INF_F 100000000.0f
#define ESC 144.26950408889634f   /* (1/gamma) * log2(e) */
#define LSC 0.006931471805599453f /* gamma * ln(2) */

__global__ __launch_bounds__(64) void sdtw_fwd_kernel(
    const float* __restrict__ input, const float* __restrict__ target,
    float4* __restrict__ Rws, double* __restrict__ partial) {
  const int b = blockIdx.x, p = threadIdx.x;
  __shared__ float xs[NN];
  const float4 xv4 = ((const float4*)(input + b * NN))[p];
  const float4 tv4 = ((const float4*)(target + b * NN))[p];
  ((float4*)xs)[p] = xv4;
  const float t0 = tv4.x, t1 = tv4.y, t2 = tv4.z, t3 = tv4.w;
  __syncthreads();

  double msel;
  {
    const float d0 = xv4.x - tv4.x, d1 = xv4.y - tv4.y;
    const float d2 = xv4.z - tv4.z, d3 = xv4.w - tv4.w;
    msel = (double)(d0 * d0) + (double)(d1 * d1) + (double)(d2 * d2) + (double)(d3 * d3);
  }

  float4* __restrict__ Rb = Rws + (size_t)b * NSLAB * PP;

  // (C,S) state: R = C - LSC*log2(S). Boundary R=INF -> (INF,1); R[0][0]=(0,1).
  float tlC = (p == 0) ? 0.0f : INF_F, tlS = 1.0f;  // R[4p][j-1]
  float ttC = INF_F, ttS = 1.0f;                    // R[4p][j]
  float pC0 = INF_F, pC1 = INF_F, pC2 = INF_F, pC3 = INF_F;  // R[rows][j-1]
  float pS0 = 1.0f, pS1 = 1.0f, pS2 = 1.0f, pS3 = 1.0f;
  // x pipeline: xu(s) = xs[clamp(s-p)], direct LDS reads prefetched 2 ahead
  float xu = xs[0];
  float xn = xs[(1 - p) < 0 ? 0 : (1 - p)];
  for (int s = 0; s < NSLAB; ++s) {
    int ix = s + 2 - p;
    ix = ix < 0 ? 0 : (ix > NN - 1 ? NN - 1 : ix);
    const float xf = xs[ix];
    const int j = s - p + 1;
    const bool act = (j >= 1) & (j <= NN);
    float eC = INF_F, eS = 1.0f;
    if (act) {
      // cell k: a=aboveleft, b=above, c=left ; chain has ONE exp2, no log2
      const float M0 = fminf(tlC, fminf(ttC, pC0));
      const float nS0 = tlS * exp2f((M0 - tlC) * ESC) + ttS * exp2f((M0 - ttC) * ESC) +
                        pS0 * exp2f((M0 - pC0) * ESC);
      const float d0 = t0 - xu;
      const float nC0 = fmaf(d0, d0, M0);
      const float M1 = fminf(pC0, fminf(nC0, pC1));
      const float nS1 = pS0 * exp2f((M1 - pC0) * ESC) + nS0 * exp2f((M1 - nC0) * ESC) +
                        pS1 * exp2f((M1 - pC1) * ESC);
      const float d1 = t1 - xu;
      const float nC1 = fmaf(d1, d1, M1);
      const float M2 = fminf(pC1, fminf(nC1, pC2));
      const float nS2 = pS1 * exp2f((M2 - pC1) * ESC) + nS1 * exp2f((M2 - nC1) * ESC) +
                        pS2 * exp2f((M2 - pC2) * ESC);
      const float d2 = t2 - xu;
      const float nC2 = fmaf(d2, d2, M2);
      const float M3 = fminf(pC2, fminf(nC2, pC3));
      const float nS3 = pS2 * exp2f((M3 - pC2) * ESC) + nS2 * exp2f((M3 - nC2) * ESC) +
                        pS3 * exp2f((M3 - pC3) * ESC);
      const float d3 = t3 - xu;
      const float nC3 = fmaf(d3, d3, M3);
      // materialize R off-chain and store for backward
      const float R0 = fmaf(-LSC, log2f(nS0), nC0);
      const float R1 = fmaf(-LSC, log2f(nS1), nC1);
      const float R2v = fmaf(-LSC, log2f(nS2), nC2);
      const float R3v = fmaf(-LSC, log2f(nS3), nC3);
      Rb[s * PP + p] = make_float4(R0, R1, R2v, R3v);
      pC0 = nC0; pS0 = nS0; pC1 = nC1; pS1 = nS1;
      pC2 = nC2; pS2 = nS2; pC3 = nC3; pS3 = nS3;
      eC = nC3; eS = nS3;
    }
    // 1-step relay of bottom-row (C,S) to lane p+1
    const float shC = __shfl_up(eC, 1);
    const float shS = __shfl_up(eS, 1);
    tlC = ttC; tlS = ttS;
    ttC = (p == 0) ? INF_F : shC;
    ttS = (p == 0) ? 1.0f : shS;
    xu = xn; xn = xf;
  }
  const float rloc = fmaf(-LSC, log2f(pS3), pC3);  // R[N][N] on lane 63
  const float r_nn = __shfl(rloc, PP - 1);

  for (int off = 32; off > 0; off >>= 1) msel += __shfl_xor(msel, off);
  if (p == 0) {
    partial[b * 4 + 0] = (double)r_nn;
    partial[b * 4 + 1] = msel;
  }
}

__global__ __launch_bounds__(64) void sdtw_bwd_kernel(
    const float* __restrict__ input, const float* __restrict__ target,
    const float4* __restrict__ Rws, double* __restrict__ partial) {
  const int b = blockIdx.x, p = threadIdx.x;
  __shared__ float xs[NN];
  const float4 xv4 = ((const float4*)(input + b * NN))[p];
  const float4 tv4 = ((const float4*)(target + b * NN))[p];
  ((float4*)xs)[p] = xv4;
  const float t0 = tv4.x, t1 = tv4.y, t2 = tv4.z, t3 = tv4.w;
  const float t4 = __shfl_down(t0, 1);  // t of row 4p+5 (pbq-guarded use)
  __syncthreads();

  const float4* __restrict__ Rb = Rws + (size_t)b * NSLAB * PP;
  // Rc(u) = slab NSLAB-1-u ; ring prefetched 3 deep (L2-resident data)
  float4 Rc = Rb[(NSLAB - 1) * PP + p];
  float4 Rc1 = Rb[(NSLAB - 2) * PP + p];
  float4 Rc2 = Rb[(NSLAB - 3) * PP + p];
  float4 Rpv = Rc;  // R(rows, j+1); unused at u=0 (jr false everywhere)
  int ixl = 318 - p;
  ixl = ixl > NN - 1 ? NN - 1 : ixl;
  float xlo = xs[ixl];     // x[j-1]
  float xhi = xs[NN - 1];  // x[j]; garbage at u=0, jr-guarded
  float Er0 = 0.f, Er1 = 0.f, Er2 = 0.f, Er3 = 0.f;  // E(rows, j+1)
  float bE0 = 0.f, bE1 = 0.f;  // E[4p+5][j], E[4p+5][j+1]
  float bR0 = 0.f, bR1 = 0.f;  // R[4p+5][j], R[4p+5][j+1]
  float seedv = (p == PP - 1) ? 1.0f : 0.0f;  // E[N][N] = 1
  const bool pbq = (p < PP - 1);
  double tsum = 0.0;

  for (int u = 0; u < NSLAB; ++u) {
    int sp = NSLAB - 4 - u;
    sp = sp < 0 ? 0 : sp;
    const float4 Rnew = Rb[sp * PP + p];
    int ixn = 317 - u - p;
    ixn = ixn < 0 ? 0 : (ixn > NN - 1 ? NN - 1 : ixn);
    const float xlo_n = xs[ixn];
    const int j = 319 - u - p;
    const bool act = (j >= 1) & (j <= NN);
    const bool jr = act & (j < NN);
    // 12 transition weights: depend only on R/x/t (all ready), NOT on E.
    float d;
    d = t1 - xlo; const float wu0 = act ? exp2f(((Rc.y - Rc.x) - d * d) * ESC) : 0.0f;
    d = t2 - xlo; const float wu1 = act ? exp2f(((Rc.z - Rc.y) - d * d) * ESC) : 0.0f;
    d = t3 - xlo; const float wu2 = act ? exp2f(((Rc.w - Rc.z) - d * d) * ESC) : 0.0f;
    d = t4 - xlo; const float wu3 = (act & pbq) ? exp2f(((bR0 - Rc.w) - d * d) * ESC) : 0.0f;
    d = t0 - xhi; const float wl0 = jr ? exp2f(((Rpv.x - Rc.x) - d * d) * ESC) : 0.0f;
    d = t1 - xhi; const float wl1 = jr ? exp2f(((Rpv.y - Rc.y) - d * d) * ESC) : 0.0f;
    d = t2 - xhi; const float wl2 = jr ? exp2f(((Rpv.z - Rc.z) - d * d) * ESC) : 0.0f;
    d = t3 - xhi; const float wl3 = jr ? exp2f(((Rpv.w - Rc.w) - d * d) * ESC) : 0.0f;
    d = t1 - xhi; const float wd0 = jr ? exp2f(((Rpv.y - Rc.x) - d * d) * ESC) : 0.0f;
    d = t2 - xhi; const float wd1 = jr ? exp2f(((Rpv.z - Rc.y) - d * d) * ESC) : 0.0f;
    d = t3 - xhi; const float wd2 = jr ? exp2f(((Rpv.w - Rc.z) - d * d) * ESC) : 0.0f;
    d = t4 - xhi; const float wd3 = (jr & pbq) ? exp2f(((bR1 - Rc.w) - d * d) * ESC) : 0.0f;
    // E chain: pure fma, 4 deep. Weights are 0 outside the window -> e == 0.
    const float e3 = wu3 * bE0 + wl3 * Er3 + wd3 * bE1 + seedv;
    const float e2 = wu2 * e3 + wl2 * Er2 + wd2 * Er3;
    const float e1 = wu1 * e2 + wl1 * Er1 + wd1 * Er2;
    const float e0 = wu0 * e1 + wl0 * Er0 + wd0 * Er1;
    // cross-lane for next step (1-step relay)
    const float sRn = __shfl_down(Rc.x, 1);
    const float sEn = __shfl_down(e0, 1);
    // temporal loss: Omega = (i-j)^2, i_k = 4p+k+1
    const float f0 = (float)(4 * p + 1 - j);
    const float f1 = f0 + 1.0f, f2 = f0 + 2.0f, f3 = f0 + 3.0f;
    tsum += (double)(e0 * f0 * f0) + (double)(e1 * f1 * f1) +
            (double)(e2 * f2 * f2) + (double)(e3 * f3 * f3);
    // rotate state
    bR1 = bR0; bR0 = sRn;
    bE1 = bE0; bE0 = sEn;
    Er0 = e0; Er1 = e1; Er2 = e2; Er3 = e3;
    Rpv = Rc; Rc = Rc1; Rc1 = Rc2; Rc2 = Rnew;
    xhi = xlo; xlo = xlo_n;
    seedv = 0.0f;
  }
  for (int off = 32; off > 0; off >>= 1) tsum += __shfl_xor(tsum, off);
  if (p == 0) partial[b * 4 + 2] = tsum;
}

__global__ __launch_bounds__(64) void finalize_kernel(const double* __restrict__ partial,
                                                      float* __restrict__ out) {
  const int t = threadIdx.x;  // one lane per batch
  double sd = partial[t * 4 + 0];
  double ms = partial[t * 4 + 1];
  double ts = partial[t * 4 + 2];
  for (int off = 32; off > 0; off >>= 1) {
    sd += __shfl_xor(sd, off);
    ms += __shfl_xor(ms, off);
    ts += __shfl_xor(ts, off);
  }
  if (t == 0) {
    const double loss_shape = sd / (double)BB;
    const double loss_temporal = ts / ((double)BB * NN * NN);
    const double mse = ms / ((double)BB * NN);
    out[0] = (float)(0.5 * loss_shape + 0.5 * loss_temporal + mse);
  }
}

extern "C" void kernel_launch(void* const* d_in, const int* in_sizes, int n_in,
                              void* d_out, int out_size, void* d_ws, size_t ws_size,
                              hipStream_t stream) {
  const float* input = (const float*)d_in[0];
  const float* target = (const float*)d_in[1];
  float4* Rws = (float4*)d_ws;
  double* partial = (double*)((char*)d_ws + (size_t)BB * NSLAB * PP * sizeof(float4));
  float* out = (float*)d_out;

  sdtw_fwd_kernel<<<BB, PP, 0, stream>>>(input, target, Rws, partial);
  sdtw_bwd_kernel<<<BB, PP, 0, stream>>>(input, target, Rws, partial);
  finalize_kernel<<<1, 64, 0, stream>>>(partial, out);
}

// Round 6
// 323.101 us; speedup vs baseline: 1.3299x; 1.2109x over previous
//
#include <hip/hip_runtime.h>
#include <math.h>

// DILATE loss: 0.5*mean(softDTW) + 0.5*sum(E*Omega)/(B*N*N) + MSE
// B=64, N=256, K=1, gamma=0.01.
//
// One wave per batch, lane p owns rows 4p+1..4p+4, skew-1 anti-diagonal scan.
// Numerics identical to R5 ((C,S) forward, weight/fma backward). This round is
// pure SCHEDULING: manual 4-body unroll with STATIC-SLOT buffers (no rotation
// copies of load destinations). Body k consumes RB_k loaded 4 steps earlier
// (3 newer loads outstanding -> counted vmcnt, latency hidden), then reloads
// RB_k for step u+4. Forward stores are branchless (dummy slab for inactive
// lanes) and 4-deep so store-ack waits are counted, not vmcnt(0).
//
// ws: [0, 64*320*64*16 B = 33.6 MB) R slabs [b][s][p] (slab 319 = dummy);
//     then 64*4 doubles.

#define BB 64
#define NN 256
#define PP 64
#define NSLAB (NN + PP - 1)  // 319 real slabs
#define NSLABP 320           // stride incl. dummy slab (index 319)
#define INF_F 100000000.0f
#define ESC 144.26950408889634f   /* (1/gamma) * log2(e) */
#define LSC 0.006931471805599453f /* gamma * ln(2) */

__device__ __forceinline__ int clampi(int v) {
  return v < 0 ? 0 : (v > NN - 1 ? NN - 1 : v);
}

// ---------------- forward ----------------
#define FWD_BODY(S, XQ)                                                        \
  {                                                                            \
    const int j_ = (S)-p + 1;                                                  \
    const bool act_ = (j_ >= 1) & (j_ <= NN);                                  \
    const float xu_ = XQ;                                                      \
    const float M0_ = fminf(tlC, fminf(ttC, pC0));                             \
    const float nS0_ = tlS * exp2f((M0_ - tlC) * ESC) +                        \
                       ttS * exp2f((M0_ - ttC) * ESC) +                        \
                       pS0 * exp2f((M0_ - pC0) * ESC);                         \
    const float d0_ = t0 - xu_;                                                \
    const float nC0_ = fmaf(d0_, d0_, M0_);                                    \
    const float M1_ = fminf(pC0, fminf(nC0_, pC1));                            \
    const float nS1_ = pS0 * exp2f((M1_ - pC0) * ESC) +                        \
                       nS0_ * exp2f((M1_ - nC0_) * ESC) +                      \
                       pS1 * exp2f((M1_ - pC1) * ESC);                         \
    const float d1_ = t1 - xu_;                                                \
    const float nC1_ = fmaf(d1_, d1_, M1_);                                    \
    const float M2_ = fminf(pC1, fminf(nC1_, pC2));                            \
    const float nS2_ = pS1 * exp2f((M2_ - pC1) * ESC) +                        \
                       nS1_ * exp2f((M2_ - nC1_) * ESC) +                      \
                       pS2 * exp2f((M2_ - pC2) * ESC);                         \
    const float d2_ = t2 - xu_;                                                \
    const float nC2_ = fmaf(d2_, d2_, M2_);                                    \
    const float M3_ = fminf(pC2, fminf(nC2_, pC3));                            \
    const float nS3_ = pS2 * exp2f((M3_ - pC2) * ESC) +                        \
                       nS2_ * exp2f((M3_ - nC2_) * ESC) +                      \
                       pS3 * exp2f((M3_ - pC3) * ESC);                         \
    const float d3_ = t3 - xu_;                                                \
    const float nC3_ = fmaf(d3_, d3_, M3_);                                    \
    const float R0_ = fmaf(-LSC, log2f(nS0_), nC0_);                           \
    const float R1_ = fmaf(-LSC, log2f(nS1_), nC1_);                           \
    const float R2_ = fmaf(-LSC, log2f(nS2_), nC2_);                           \
    const float R3_ = fmaf(-LSC, log2f(nS3_), nC3_);                           \
    const int slab_ = act_ ? (S) : (NSLABP - 1);                               \
    Rb[(size_t)slab_ * PP + p] = make_float4(R0_, R1_, R2_, R3_);              \
    pC0 = act_ ? nC0_ : pC0; pS0 = act_ ? nS0_ : pS0;                          \
    pC1 = act_ ? nC1_ : pC1; pS1 = act_ ? nS1_ : pS1;                          \
    pC2 = act_ ? nC2_ : pC2; pS2 = act_ ? nS2_ : pS2;                          \
    pC3 = act_ ? nC3_ : pC3; pS3 = act_ ? nS3_ : pS3;                          \
    const float shC_ = __shfl_up(act_ ? nC3_ : INF_F, 1);                      \
    const float shS_ = __shfl_up(act_ ? nS3_ : 1.0f, 1);                       \
    tlC = ttC; tlS = ttS;                                                      \
    ttC = (p == 0) ? INF_F : shC_;                                             \
    ttS = (p == 0) ? 1.0f : shS_;                                              \
    XQ = xs[clampi((S) + 4 - p)];                                              \
  }

__global__ __launch_bounds__(64, 1) void sdtw_fwd_kernel(
    const float* __restrict__ input, const float* __restrict__ target,
    float4* __restrict__ Rws, double* __restrict__ partial) {
  const int b = blockIdx.x, p = threadIdx.x;
  __shared__ float xs[NN];
  const float4 xv4 = ((const float4*)(input + b * NN))[p];
  const float4 tv4 = ((const float4*)(target + b * NN))[p];
  ((float4*)xs)[p] = xv4;
  const float t0 = tv4.x, t1 = tv4.y, t2 = tv4.z, t3 = tv4.w;
  __syncthreads();

  double msel;
  {
    const float d0 = xv4.x - tv4.x, d1 = xv4.y - tv4.y;
    const float d2 = xv4.z - tv4.z, d3 = xv4.w - tv4.w;
    msel = (double)(d0 * d0) + (double)(d1 * d1) + (double)(d2 * d2) + (double)(d3 * d3);
  }

  float4* __restrict__ Rb = Rws + (size_t)b * NSLABP * PP;

  // (C,S) state: R = C - LSC*log2(S). Boundary R=INF -> (INF,1); R[0][0]=(0,1).
  float tlC = (p == 0) ? 0.0f : INF_F, tlS = 1.0f;
  float ttC = INF_F, ttS = 1.0f;
  float pC0 = INF_F, pC1 = INF_F, pC2 = INF_F, pC3 = INF_F;
  float pS0 = 1.0f, pS1 = 1.0f, pS2 = 1.0f, pS3 = 1.0f;
  // static x slots (slot k serves steps ≡ k mod 4; refilled 4 ahead)
  float xq0 = xs[clampi(0 - p)];
  float xq1 = xs[clampi(1 - p)];
  float xq2 = xs[clampi(2 - p)];
  float xq3 = xs[clampi(3 - p)];

  for (int s = 0; s < NSLABP; s += 4) {  // 320 steps; s=319 inactive for all lanes
    FWD_BODY(s + 0, xq0)
    FWD_BODY(s + 1, xq1)
    FWD_BODY(s + 2, xq2)
    FWD_BODY(s + 3, xq3)
  }
  const float rloc = fmaf(-LSC, log2f(pS3), pC3);  // R[N][N] on lane 63
  const float r_nn = __shfl(rloc, PP - 1);

  for (int off = 32; off > 0; off >>= 1) msel += __shfl_xor(msel, off);
  if (p == 0) {
    partial[b * 4 + 0] = (double)r_nn;
    partial[b * 4 + 1] = msel;
  }
}

// ---------------- backward ----------------
#define BWD_BODY(U, RBUF, XQ)                                                  \
  {                                                                            \
    const int j_ = NSLAB - (U)-p;                                              \
    const bool act_ = (j_ >= 1) & (j_ <= NN);                                  \
    const bool jr_ = act_ & (j_ < NN);                                         \
    const float4 Rc_ = RBUF;                                                   \
    const float xlo_ = XQ;                                                     \
    float d_;                                                                  \
    d_ = t1 - xlo_;                                                            \
    const float wu0_ = act_ ? exp2f(((Rc_.y - Rc_.x) - d_ * d_) * ESC) : 0.0f; \
    d_ = t2 - xlo_;                                                            \
    const float wu1_ = act_ ? exp2f(((Rc_.z - Rc_.y) - d_ * d_) * ESC) : 0.0f; \
    d_ = t3 - xlo_;                                                            \
    const float wu2_ = act_ ? exp2f(((Rc_.w - Rc_.z) - d_ * d_) * ESC) : 0.0f; \
    d_ = t4 - xlo_;                                                            \
    const float wu3_ =                                                         \
        (act_ & pbq) ? exp2f(((bR0 - Rc_.w) - d_ * d_) * ESC) : 0.0f;          \
    d_ = t0 - xhi;                                                             \
    const float wl0_ = jr_ ? exp2f(((Rpv.x - Rc_.x) - d_ * d_) * ESC) : 0.0f;  \
    d_ = t1 - xhi;                                                             \
    const float wl1_ = jr_ ? exp2f(((Rpv.y - Rc_.y) - d_ * d_) * ESC) : 0.0f;  \
    d_ = t2 - xhi;                                                             \
    const float wl2_ = jr_ ? exp2f(((Rpv.z - Rc_.z) - d_ * d_) * ESC) : 0.0f;  \
    d_ = t3 - xhi;                                                             \
    const float wl3_ = jr_ ? exp2f(((Rpv.w - Rc_.w) - d_ * d_) * ESC) : 0.0f;  \
    d_ = t1 - xhi;                                                             \
    const float wd0_ = jr_ ? exp2f(((Rpv.y - Rc_.x) - d_ * d_) * ESC) : 0.0f;  \
    d_ = t2 - xhi;                                                             \
    const float wd1_ = jr_ ? exp2f(((Rpv.z - Rc_.y) - d_ * d_) * ESC) : 0.0f;  \
    d_ = t3 - xhi;                                                             \
    const float wd2_ = jr_ ? exp2f(((Rpv.w - Rc_.z) - d_ * d_) * ESC) : 0.0f;  \
    d_ = t4 - xhi;                                                             \
    const float wd3_ =                                                         \
        (jr_ & pbq) ? exp2f(((bR1 - Rc_.w) - d_ * d_) * ESC) : 0.0f;           \
    const float seed_ = ((p == PP - 1) & ((U) == 0)) ? 1.0f : 0.0f;            \
    const float e3_ = wu3_ * bE0 + wl3_ * Er3 + wd3_ * bE1 + seed_;            \
    const float e2_ = wu2_ * e3_ + wl2_ * Er2 + wd2_ * Er3;                    \
    const float e1_ = wu1_ * e2_ + wl1_ * Er1 + wd1_ * Er2;                    \
    const float e0_ = wu0_ * e1_ + wl0_ * Er0 + wd0_ * Er1;                    \
    const float sRn_ = __shfl_down(Rc_.x, 1);                                  \
    const float sEn_ = __shfl_down(e0_, 1);                                    \
    const float f0_ = (float)(4 * p + 1 - j_);                                 \
    const float f1_ = f0_ + 1.0f, f2_ = f0_ + 2.0f, f3_ = f0_ + 3.0f;          \
    tsum += (double)(e0_ * f0_ * f0_) + (double)(e1_ * f1_ * f1_) +            \
            (double)(e2_ * f2_ * f2_) + (double)(e3_ * f3_ * f3_);             \
    bR1 = bR0; bR0 = sRn_;                                                     \
    bE1 = bE0; bE0 = sEn_;                                                     \
    Er0 = e0_; Er1 = e1_; Er2 = e2_; Er3 = e3_;                                \
    Rpv = Rc_;                                                                 \
    xhi = xlo_;                                                                \
    {                                                                          \
      int sp_ = NSLAB - 1 - ((U) + 4);                                         \
      sp_ = sp_ < 0 ? 0 : sp_;                                                 \
      RBUF = Rb[(size_t)sp_ * PP + p];                                         \
    }                                                                          \
    XQ = xs[clampi(NSLAB - 1 - ((U) + 4) - p)];                                \
  }

__global__ __launch_bounds__(64, 1) void sdtw_bwd_kernel(
    const float* __restrict__ input, const float* __restrict__ target,
    const float4* __restrict__ Rws, double* __restrict__ partial) {
  const int b = blockIdx.x, p = threadIdx.x;
  __shared__ float xs[NN];
  const float4 xv4 = ((const float4*)(input + b * NN))[p];
  const float4 tv4 = ((const float4*)(target + b * NN))[p];
  ((float4*)xs)[p] = xv4;
  const float t0 = tv4.x, t1 = tv4.y, t2 = tv4.z, t3 = tv4.w;
  const float t4 = __shfl_down(t0, 1);  // t of row 4p+5 (pbq-guarded use)
  __syncthreads();

  const float4* __restrict__ Rb = Rws + (size_t)b * NSLABP * PP;
  // static slots: RB_k / xq_k serve steps ≡ k (mod 4), preloaded for u=0..3
  float4 RB0 = Rb[(size_t)(NSLAB - 1) * PP + p];
  float4 RB1 = Rb[(size_t)(NSLAB - 2) * PP + p];
  float4 RB2 = Rb[(size_t)(NSLAB - 3) * PP + p];
  float4 RB3 = Rb[(size_t)(NSLAB - 4) * PP + p];
  float xq0 = xs[clampi(NSLAB - 1 - 0 - p)];
  float xq1 = xs[clampi(NSLAB - 1 - 1 - p)];
  float xq2 = xs[clampi(NSLAB - 1 - 2 - p)];
  float xq3 = xs[clampi(NSLAB - 1 - 3 - p)];
  float4 Rpv = make_float4(0.f, 0.f, 0.f, 0.f);  // unused at u=0 (jr_ false)
  float xhi = 0.0f;                              // unused at u=0
  float Er0 = 0.f, Er1 = 0.f, Er2 = 0.f, Er3 = 0.f;
  float bR0 = 0.f, bR1 = 0.f, bE0 = 0.f, bE1 = 0.f;
  const bool pbq = (p < PP - 1);
  double tsum = 0.0;

  for (int u = 0; u < NSLABP; u += 4) {  // 320 steps; u=319 inactive for all lanes
    BWD_BODY(u + 0, RB0, xq0)
    BWD_BODY(u + 1, RB1, xq1)
    BWD_BODY(u + 2, RB2, xq2)
    BWD_BODY(u + 3, RB3, xq3)
  }
  for (int off = 32; off > 0; off >>= 1) tsum += __shfl_xor(tsum, off);
  if (p == 0) partial[b * 4 + 2] = tsum;
}

__global__ __launch_bounds__(64) void finalize_kernel(const double* __restrict__ partial,
                                                      float* __restrict__ out) {
  const int t = threadIdx.x;  // one lane per batch
  double sd = partial[t * 4 + 0];
  double ms = partial[t * 4 + 1];
  double ts = partial[t * 4 + 2];
  for (int off = 32; off > 0; off >>= 1) {
    sd += __shfl_xor(sd, off);
    ms += __shfl_xor(ms, off);
    ts += __shfl_xor(ts, off);
  }
  if (t == 0) {
    const double loss_shape = sd / (double)BB;
    const double loss_temporal = ts / ((double)BB * NN * NN);
    const double mse = ms / ((double)BB * NN);
    out[0] = (float)(0.5 * loss_shape + 0.5 * loss_temporal + mse);
  }
}

extern "C" void kernel_launch(void* const* d_in, const int* in_sizes, int n_in,
                              void* d_out, int out_size, void* d_ws, size_t ws_size,
                              hipStream_t stream) {
  const float* input = (const float*)d_in[0];
  const float* target = (const float*)d_in[1];
  float4* Rws = (float4*)d_ws;
  double* partial = (double*)((char*)d_ws + (size_t)BB * NSLABP * PP * sizeof(float4));
  float* out = (float*)d_out;

  sdtw_fwd_kernel<<<BB, PP, 0, stream>>>(input, target, Rws, partial);
  sdtw_bwd_kernel<<<BB, PP, 0, stream>>>(input, target, Rws, partial);
  finalize_kernel<<<1, 64, 0, stream>>>(partial, out);
}